// Round 1
// 395.643 us; speedup vs baseline: 1.0638x; 1.0638x over previous
//
#include <hip/hip_runtime.h>
#include <hip/hip_bf16.h>

// Problem constants
#define B_   16
#define C_   512
#define HW_  2304
#define NH_  8
#define SCALE_ 0.125f

typedef __bf16 bf16x8 __attribute__((ext_vector_type(8)));
typedef __bf16 bf16x4 __attribute__((ext_vector_type(4)));
typedef float  f32x4  __attribute__((ext_vector_type(4)));

#define MFMA16(a, b, c) __builtin_amdgcn_mfma_f32_16x16x32_bf16((a), (b), (c), 0, 0, 0)

// async global->LDS, 16B/lane; LDS dest = wave-uniform base + lane*16
__device__ __forceinline__ void gload_lds16(const void* g, void* l) {
    __builtin_amdgcn_global_load_lds(
        (const __attribute__((address_space(1))) unsigned int*)g,
        (__attribute__((address_space(3))) unsigned int*)l, 16, 0, 0);
}

__device__ __forceinline__ bf16x8 pack8(const float4 a, const float4 b) {
    bf16x8 o;
    o[0] = (__bf16)a.x; o[1] = (__bf16)a.y; o[2] = (__bf16)a.z; o[3] = (__bf16)a.w;
    o[4] = (__bf16)b.x; o[5] = (__bf16)b.y; o[6] = (__bf16)b.z; o[7] = (__bf16)b.w;
    return o;
}

// ---------------------------------------------------------------------------
// Weight prep: Wq,Wk,Wo fp32->bf16 (plain); Wv fp32->bf16 TRANSPOSED (WvT[c][o]).
// grid (128, 4), 256 threads.
// ---------------------------------------------------------------------------
__global__ __launch_bounds__(256) void wprep(
    const float* __restrict__ Wq, const float* __restrict__ Wk,
    const float* __restrict__ Wv, const float* __restrict__ Wo,
    __bf16* __restrict__ WqB, __bf16* __restrict__ WkB,
    __bf16* __restrict__ WvT, __bf16* __restrict__ WoB)
{
    const int t = threadIdx.x;
    if (blockIdx.y < 3) {
        const float* src = blockIdx.y == 0 ? Wq : blockIdx.y == 1 ? Wk : Wo;
        __bf16*      dst = blockIdx.y == 0 ? WqB : blockIdx.y == 1 ? WkB : WoB;
        const int idx = blockIdx.x * 2048 + t * 8;
        const float4 f0 = *(const float4*)&src[idx];
        const float4 f1 = *(const float4*)&src[idx + 4];
        *(bf16x8*)&dst[idx] = pack8(f0, f1);
        return;
    }
    // y == 3: WvT transpose, 64 tiles of 64x64
    if (blockIdx.x >= 64) return;
    const int tx = blockIdx.x & 7, ty = blockIdx.x >> 3;
    __shared__ float Ts[64 * 65];
    {
        const int r = t >> 2, c0 = (t & 3) * 16;
        #pragma unroll
        for (int j = 0; j < 4; ++j) {
            const float4 v = *(const float4*)&Wv[(size_t)(ty * 64 + r) * C_ + tx * 64 + c0 + j * 4];
            Ts[r * 65 + c0 + j * 4 + 0] = v.x;
            Ts[r * 65 + c0 + j * 4 + 1] = v.y;
            Ts[r * 65 + c0 + j * 4 + 2] = v.z;
            Ts[r * 65 + c0 + j * 4 + 3] = v.w;
        }
    }
    __syncthreads();
    {
        const int c = t >> 2, r0 = (t & 3) * 16;
        bf16x8 o0, o1;
        #pragma unroll
        for (int j = 0; j < 8; ++j) {
            o0[j] = (__bf16)Ts[(r0 + j) * 65 + c];
            o1[j] = (__bf16)Ts[(r0 + 8 + j) * 65 + c];
        }
        *(bf16x8*)&WvT[(size_t)(tx * 64 + c) * C_ + ty * 64 + r0]     = o0;
        *(bf16x8*)&WvT[(size_t)(tx * 64 + c) * C_ + ty * 64 + r0 + 8] = o1;
    }
}

// ---------------------------------------------------------------------------
// prep: transpose+convert X[b][c][hw] fp32 -> XT[b][hw][c] bf16 (Xv only now).
// grid (18, 8, 16), 256 threads.  (verified kernel from prior rounds)
// ---------------------------------------------------------------------------
__global__ __launch_bounds__(256) void prep(
    const float* __restrict__ X, __bf16* __restrict__ XT)
{
    const int t  = threadIdx.x;
    const int b  = blockIdx.z;
    const int c0 = blockIdx.y * 64;
    const int h0 = blockIdx.x * 128;
    const float* Xb = X + (size_t)b * C_ * HW_;
    __bf16* XTb = XT + (size_t)b * HW_ * C_;

    __shared__ float Ts[64 * 129];

    #pragma unroll
    for (int p = 0; p < 8; ++p) {
        const int c  = p * 8 + (t >> 5);
        const int hg = (t & 31) * 4;
        const float4 v = *(const float4*)&Xb[(size_t)(c0 + c) * HW_ + h0 + hg];
        Ts[c * 129 + hg + 0] = v.x;
        Ts[c * 129 + hg + 1] = v.y;
        Ts[c * 129 + hg + 2] = v.z;
        Ts[c * 129 + hg + 3] = v.w;
    }
    __syncthreads();
    #pragma unroll
    for (int p = 0; p < 4; ++p) {
        const int hw = p * 32 + (t >> 3);
        const int g  = (t & 7) * 8;
        bf16x8 o;
        #pragma unroll
        for (int e = 0; e < 8; ++e)
            o[e] = (__bf16)Ts[(g + e) * 129 + hw];
        *(bf16x8*)&XTb[(size_t)(h0 + hw) * C_ + c0 + g] = o;
    }
}

// ---------------------------------------------------------------------------
// gxx: G'[b][c2][c1] = sum_hw Xk[b][c2][hw] * Xq[b][c1][hw]  (bf16 out)
// plus row sums xksum[b][c2] (by n0==0 blocks), xqsum[b][c1] (by m0==0 blocks).
// fp32 inputs are K-contiguous already; fp32->bf16 fused into reg->LDS staging.
// grid (256) 1-D with whole-batch-per-XCD swizzle; 512 threads (8 waves).
// ---------------------------------------------------------------------------
__global__ __launch_bounds__(512) void gxx(
    const float* __restrict__ Xk, const float* __restrict__ Xq,
    __bf16* __restrict__ Gp, float* __restrict__ xksum, float* __restrict__ xqsum)
{
    const int i    = blockIdx.x;
    const int xcd  = i & 7, slot = i >> 3;
    const int b    = xcd + 8 * (slot & 1);       // 2 batches per XCD -> L2 reuse
    const int xy   = slot >> 1;                  // 0..15
    const int n0   = (xy & 3) * 128;             // c1 tile (Xq rows)
    const int m0   = (xy >> 2) * 128;            // c2 tile (Xk rows)

    __shared__ __align__(16) __bf16 As[128 * 64];
    __shared__ __align__(16) __bf16 Bs[128 * 64];

    const int t = threadIdx.x, w = t >> 6, lane = t & 63, l16 = lane & 15, q = lane >> 4;
    const int wm = w >> 1, wn = w & 1;           // 4x2 wave grid: 32x64 per wave
    const int r = t >> 2, qq = t & 3;            // staging: 4 threads/row, 16 cols each

    const float* Ap = Xk + (size_t)b * C_ * HW_ + (size_t)(m0 + r) * HW_ + qq * 16;
    const float* Bp = Xq + (size_t)b * C_ * HW_ + (size_t)(n0 + r) * HW_ + qq * 16;

    float4 av[4], bv[4];
    #pragma unroll
    for (int j = 0; j < 4; ++j) {
        av[j] = *(const float4*)&Ap[j * 4];
        bv[j] = *(const float4*)&Bp[j * 4];
    }

    const bool doA = (n0 == 0), doB = (m0 == 0);
    float sA = 0.f, sB = 0.f;
    f32x4 acc[2][4] = {};

    for (int ks = 0; ks < 36; ++ks) {
        if (ks) __syncthreads();
        if (doA) {
            #pragma unroll
            for (int j = 0; j < 4; ++j) sA += av[j].x + av[j].y + av[j].z + av[j].w;
        }
        if (doB) {
            #pragma unroll
            for (int j = 0; j < 4; ++j) sB += bv[j].x + bv[j].y + bv[j].z + bv[j].w;
        }
        #pragma unroll
        for (int jj = 0; jj < 2; ++jj) {
            const int g  = qq * 2 + jj;
            const int sw = (g ^ (r & 7)) * 8;
            *(bf16x8*)&As[r * 64 + sw] = pack8(av[jj * 2], av[jj * 2 + 1]);
            *(bf16x8*)&Bs[r * 64 + sw] = pack8(bv[jj * 2], bv[jj * 2 + 1]);
        }
        __syncthreads();
        if (ks + 1 < 36) {                       // prefetch next slab (in flight over MFMA)
            const int off = (ks + 1) * 64;
            #pragma unroll
            for (int j = 0; j < 4; ++j) {
                av[j] = *(const float4*)&Ap[off + j * 4];
                bv[j] = *(const float4*)&Bp[off + j * 4];
            }
        }
        #pragma unroll
        for (int kk = 0; kk < 2; ++kk) {
            const int sw = ((kk * 4 + q) ^ (l16 & 7)) * 8;
            bf16x8 af[2], bfr[4];
            #pragma unroll
            for (int mi = 0; mi < 2; ++mi)
                af[mi] = *(bf16x8*)&As[(wm * 32 + mi * 16 + l16) * 64 + sw];
            #pragma unroll
            for (int ni = 0; ni < 4; ++ni)
                bfr[ni] = *(bf16x8*)&Bs[(wn * 64 + ni * 16 + l16) * 64 + sw];
            #pragma unroll
            for (int mi = 0; mi < 2; ++mi)
                #pragma unroll
                for (int ni = 0; ni < 4; ++ni)
                    acc[mi][ni] = MFMA16(af[mi], bfr[ni], acc[mi][ni]);
        }
    }

    if (doA) {
        float s = sA; s += __shfl_xor(s, 1); s += __shfl_xor(s, 2);
        if (qq == 0) xksum[b * C_ + m0 + r] = s;
    }
    if (doB) {
        float s = sB; s += __shfl_xor(s, 1); s += __shfl_xor(s, 2);
        if (qq == 0) xqsum[b * C_ + n0 + r] = s;
    }

    __bf16* Gb = Gp + (size_t)b * C_ * C_;
    #pragma unroll
    for (int mi = 0; mi < 2; ++mi)
        #pragma unroll
        for (int rr = 0; rr < 4; ++rr) {
            const int m = m0 + wm * 32 + mi * 16 + q * 4 + rr;
            #pragma unroll
            for (int ni = 0; ni < 4; ++ni) {
                const int n = n0 + wn * 64 + ni * 16 + l16;
                Gb[(size_t)m * C_ + n] = (__bf16)acc[mi][ni][rr];
            }
        }
}

// ---------------------------------------------------------------------------
// scoresk: per (b,nh): T = Wq_nh * G'^T (64x512), S = T * Wk_nh^T (64x64),
// + rank-1 bias terms, softmax, write P bf16.  grid (128) 1-D, 512 threads.
// ---------------------------------------------------------------------------
__global__ __launch_bounds__(512) void scoresk(
    const __bf16* __restrict__ Gp, const __bf16* __restrict__ WqB,
    const __bf16* __restrict__ WkB, const float* __restrict__ xqsum,
    const float* __restrict__ xksum, const float* __restrict__ bq,
    const float* __restrict__ bk, __bf16* __restrict__ P)
{
    const int i  = blockIdx.x;
    const int b  = (i & 7) + 8 * ((i >> 3) & 1); // batch on one XCD (G' L2 reuse)
    const int nh = i >> 4;

    __shared__ __align__(16) __bf16 Gs[512 * 64];   // G' slab, later Ts[64][512]
    __shared__ __align__(16) __bf16 Ws[64 * 64];    // Wq tile, later Wk tile
    __shared__ float Ss[64 * 64];
    __shared__ float aqs[64], aks[64];

    const int t = threadIdx.x, w = t >> 6, lane = t & 63, l16 = lane & 15, q = lane >> 4;

    // aq = Wq_nh * xqsum, ak = Wk_nh * xksum  (rank-1 bias helpers)
    {
        const int h = t >> 3, seg = (t & 7) * 64;
        const __bf16* wr1 = WqB + (size_t)(nh * 64 + h) * C_ + seg;
        const __bf16* wr2 = WkB + (size_t)(nh * 64 + h) * C_ + seg;
        const float* x1 = xqsum + b * C_ + seg;
        const float* x2 = xksum + b * C_ + seg;
        float s1 = 0.f, s2 = 0.f;
        #pragma unroll
        for (int e = 0; e < 64; e += 8) {
            const bf16x8 v1 = *(const bf16x8*)&wr1[e];
            const bf16x8 v2 = *(const bf16x8*)&wr2[e];
            #pragma unroll
            for (int j = 0; j < 8; ++j) {
                s1 += (float)v1[j] * x1[e + j];
                s2 += (float)v2[j] * x2[e + j];
            }
        }
        s1 += __shfl_xor(s1, 1); s1 += __shfl_xor(s1, 2); s1 += __shfl_xor(s1, 4);
        s2 += __shfl_xor(s2, 1); s2 += __shfl_xor(s2, 2); s2 += __shfl_xor(s2, 4);
        if ((t & 7) == 0) { aqs[h] = s1; aks[h] = s2; }
    }

    // --- T-step: wave (hf, ch) computes T[hf*16..+15][ch*256..+255] ---
    const int hf = w >> 1, ch = w & 1;
    const __bf16* Gb = Gp + (size_t)b * C_ * C_;
    f32x4 acc[16] = {};

    for (int ks = 0; ks < 8; ++ks) {
        const int k0 = ks * 64;
        __syncthreads();
        {
            const int row = t >> 3;
            const int sg  = ((lane & 7) ^ (row & 7)) * 8;
            gload_lds16(&WqB[(size_t)(nh * 64 + row) * C_ + k0 + sg], &Ws[(w * 8) * 64]);
        }
        #pragma unroll
        for (int p = 0; p < 8; ++p) {
            const int row = p * 64 + w * 8 + (lane >> 3);
            const int sg  = ((lane & 7) ^ (row & 7)) * 8;
            gload_lds16(&Gb[(size_t)row * C_ + k0 + sg], &Gs[(p * 64 + w * 8) * 64]);
        }
        __syncthreads();
        #pragma unroll
        for (int kk = 0; kk < 2; ++kk) {
            const int sw = ((kk * 4 + q) ^ (l16 & 7)) * 8;
            const bf16x8 a = *(const bf16x8*)&Ws[(hf * 16 + l16) * 64 + sw];
            #pragma unroll
            for (int ni = 0; ni < 16; ++ni) {
                const bf16x8 g = *(const bf16x8*)&Gs[(ch * 256 + ni * 16 + l16) * 64 + sw];
                acc[ni] = MFMA16(a, g, acc[ni]);
            }
        }
    }

    __syncthreads();
    // T -> Ts bf16 (in Gs storage), granule-swizzled by row for conflict-free reads
    #pragma unroll
    for (int ni = 0; ni < 16; ++ni) {
        const int c2 = ch * 256 + ni * 16 + l16;
        #pragma unroll
        for (int rr = 0; rr < 4; ++rr) {
            const int h = hf * 16 + q * 4 + rr;
            Gs[h * 512 + (((c2 >> 3) ^ (h & 7)) << 3) + (c2 & 7)] = (__bf16)acc[ni][rr];
        }
    }
    __syncthreads();

    // --- S-step: S[h][k] = sum_c2 T[h][c2] Wk[nh*64+k][c2] ---
    f32x4 sacc[2] = {};
    const int kf0 = (w & 1) * 2;
    for (int ks = 0; ks < 8; ++ks) {
        if (ks) __syncthreads();
        {
            const int row = t >> 3;
            const int sg  = ((lane & 7) ^ (row & 7)) * 8;
            gload_lds16(&WkB[(size_t)(nh * 64 + row) * C_ + ks * 64 + sg], &Ws[(w * 8) * 64]);
        }
        __syncthreads();
        #pragma unroll
        for (int kk = 0; kk < 2; ++kk) {
            const int h = hf * 16 + l16;
            const int g = ks * 8 + kk * 4 + q;
            const bf16x8 a = *(const bf16x8*)&Gs[h * 512 + ((g ^ (h & 7)) << 3)];
            const int swb = ((kk * 4 + q) ^ (l16 & 7)) * 8;
            #pragma unroll
            for (int kf = 0; kf < 2; ++kf) {
                const bf16x8 bb = *(const bf16x8*)&Ws[((kf0 + kf) * 16 + l16) * 64 + swb];
                sacc[kf] = MFMA16(a, bb, sacc[kf]);
            }
        }
    }

    #pragma unroll
    for (int kf = 0; kf < 2; ++kf)
        #pragma unroll
        for (int rr = 0; rr < 4; ++rr)
            Ss[(hf * 16 + q * 4 + rr) * 64 + (kf0 + kf) * 16 + l16] = sacc[kf][rr];
    __syncthreads();

    // softmax per row (8 threads/row) + rank-1 bias terms
    {
        const int h = t >> 3, j0 = (t & 7) * 8;
        const float bqv = bq[nh * 64 + h];
        const float aqv = aqs[h];
        float v[8];
        float mx = -1e30f;
        #pragma unroll
        for (int j = 0; j < 8; ++j) {
            const int k = j0 + j;
            const float bkv = bk[nh * 64 + k];
            v[j] = SCALE_ * (Ss[h * 64 + k] + aqv * bkv + bqv * (aks[k] + (float)HW_ * bkv));
            mx = fmaxf(mx, v[j]);
        }
        mx = fmaxf(mx, __shfl_xor(mx, 1));
        mx = fmaxf(mx, __shfl_xor(mx, 2));
        mx = fmaxf(mx, __shfl_xor(mx, 4));
        float sum = 0.f;
        #pragma unroll
        for (int j = 0; j < 8; ++j) { v[j] = __expf(v[j] - mx); sum += v[j]; }
        sum += __shfl_xor(sum, 1); sum += __shfl_xor(sum, 2); sum += __shfl_xor(sum, 4);
        const float inv = 1.f / sum;
        bf16x8 o;
        #pragma unroll
        for (int j = 0; j < 8; ++j) o[j] = (__bf16)(v[j] * inv);
        *(bf16x8*)&P[(((size_t)b * NH_ + nh) * 64 + h) * 64 + j0] = o;
    }
}

// ---------------------------------------------------------------------------
// pwv: per (b,n): W2T[c][n*64+h] = sum_k P[h][k] WvT[c][n*64+k]  (bf16),
// plus beta[n*64+h] = P_row . bv.  grid (8,16), 512 threads.
// ---------------------------------------------------------------------------
__global__ __launch_bounds__(512) void pwv(
    const __bf16* __restrict__ P, const __bf16* __restrict__ WvT,
    const float* __restrict__ bv, __bf16* __restrict__ W2T, float* __restrict__ Bb)
{
    const int n = blockIdx.x, b = blockIdx.y;
    __shared__ __align__(16) __bf16 Ps[64 * 64];
    __shared__ __align__(16) __bf16 Vs[512 * 64];
    __shared__ __align__(16) __bf16 W2s[8][64 * 72];   // per-wave transpose buffer

    const int t = threadIdx.x, w = t >> 6, lane = t & 63, l16 = lane & 15, q = lane >> 4;

    {
        const int row = t >> 3;
        const int sg  = ((lane & 7) ^ (row & 7)) * 8;
        gload_lds16(&P[(((size_t)b * NH_ + n) * 64 + row) * 64 + sg], &Ps[(w * 8) * 64]);
    }
    #pragma unroll
    for (int p = 0; p < 8; ++p) {
        const int row = p * 64 + w * 8 + (lane >> 3);
        const int sg  = ((lane & 7) ^ (row & 7)) * 8;
        gload_lds16(&WvT[(size_t)row * C_ + n * 64 + sg], &Vs[(p * 64 + w * 8) * 64]);
    }
    __syncthreads();

    // beta
    {
        const int h = t >> 3, g = t & 7;
        const bf16x8 pv = *(const bf16x8*)&Ps[h * 64 + ((g ^ (h & 7)) << 3)];
        float s = 0.f;
        #pragma unroll
        for (int j = 0; j < 8; ++j) s += (float)pv[j] * bv[n * 64 + g * 8 + j];
        s += __shfl_xor(s, 1); s += __shfl_xor(s, 2); s += __shfl_xor(s, 4);
        if (g == 0) Bb[b * C_ + n * 64 + h] = s;
    }

    // wave w owns c in [w*64, +64)
    f32x4 acc[4][4] = {};
    #pragma unroll
    for (int kk = 0; kk < 2; ++kk) {
        const int sw = ((kk * 4 + q) ^ (l16 & 7)) * 8;
        bf16x8 af[4], bfr[4];
        #pragma unroll
        for (int hf = 0; hf < 4; ++hf)
            af[hf] = *(const bf16x8*)&Ps[(hf * 16 + l16) * 64 + sw];
        #pragma unroll
        for (int ni = 0; ni < 4; ++ni)
            bfr[ni] = *(const bf16x8*)&Vs[(w * 64 + ni * 16 + l16) * 64 + sw];
        #pragma unroll
        for (int hf = 0; hf < 4; ++hf)
            #pragma unroll
            for (int ni = 0; ni < 4; ++ni)
                acc[hf][ni] = MFMA16(af[hf], bfr[ni], acc[hf][ni]);
    }

    // transpose through LDS so W2T global writes are coalesced along m
    #pragma unroll
    for (int hf = 0; hf < 4; ++hf)
        #pragma unroll
        for (int ni = 0; ni < 4; ++ni) {
            const int cl = ni * 16 + l16;
            bf16x4 o;
            #pragma unroll
            for (int rr = 0; rr < 4; ++rr) o[rr] = (__bf16)acc[hf][ni][rr];
            *(bf16x4*)&W2s[w][cl * 72 + hf * 16 + q * 4] = o;
        }
    __syncthreads();
    #pragma unroll
    for (int p = 0; p < 8; ++p) {
        const int cl = p * 8 + (lane >> 3);
        const int g  = lane & 7;
        const bf16x8 v = *(const bf16x8*)&W2s[w][cl * 72 + g * 8];
        *(bf16x8*)&W2T[((size_t)b * C_ + w * 64 + cl) * C_ + n * 64 + g * 8] = v;
    }
}

// ---------------------------------------------------------------------------
// ugemm: U[b][o][c] = sum_m Wo[o][m] * W2T[b][c][m]  (bf16), 8-wave 128x128.
// Also f_b[b][o] = Wo[o].beta_b + bo[o]  (blocks with x==0).
// grid (4,4,16), 512 threads.
// ---------------------------------------------------------------------------
__global__ __launch_bounds__(512) void ugemm(
    const __bf16* __restrict__ W2T, const __bf16* __restrict__ WoB,
    __bf16* __restrict__ U, const float* __restrict__ Bb,
    const float* __restrict__ bo, float* __restrict__ fb)
{
    const int b  = blockIdx.z;
    const int n0 = blockIdx.x * 128;   // c
    const int m0 = blockIdx.y * 128;   // o
    const __bf16* Bn = W2T + (size_t)b * C_ * C_;

    __shared__ __align__(16) __bf16 As[128 * 64];
    __shared__ __align__(16) __bf16 Bs[128 * 64];

    const int t = threadIdx.x, w = t >> 6, lane = t & 63, l16 = lane & 15, q = lane >> 4;
    const int wm = w >> 1, wn = w & 1;
    const int sr = lane >> 3;
    const int sg = ((lane & 7) ^ sr) * 8;

    f32x4 acc[2][4] = {};
    for (int ks = 0; ks < 8; ++ks) {
        const int k0 = ks * 64;
        __syncthreads();
        #pragma unroll
        for (int p = 0; p < 2; ++p) {
            const int rb = p * 64 + w * 8;
            gload_lds16(&WoB[(size_t)(m0 + rb + sr) * C_ + k0 + sg], &As[rb * 64]);
            gload_lds16(&Bn [(size_t)(n0 + rb + sr) * C_ + k0 + sg], &Bs[rb * 64]);
        }
        __syncthreads();
        #pragma unroll
        for (int kk = 0; kk < 2; ++kk) {
            const int sw = ((kk * 4 + q) ^ (l16 & 7)) * 8;
            bf16x8 af[2], bfr[4];
            #pragma unroll
            for (int mi = 0; mi < 2; ++mi)
                af[mi] = *(bf16x8*)&As[(wm * 32 + mi * 16 + l16) * 64 + sw];
            #pragma unroll
            for (int ni = 0; ni < 4; ++ni)
                bfr[ni] = *(bf16x8*)&Bs[(wn * 64 + ni * 16 + l16) * 64 + sw];
            #pragma unroll
            for (int mi = 0; mi < 2; ++mi)
                #pragma unroll
                for (int ni = 0; ni < 4; ++ni)
                    acc[mi][ni] = MFMA16(af[mi], bfr[ni], acc[mi][ni]);
        }
    }

    __bf16* Ub = U + (size_t)b * C_ * C_;
    #pragma unroll
    for (int mi = 0; mi < 2; ++mi)
        #pragma unroll
        for (int rr = 0; rr < 4; ++rr) {
            const int m = m0 + wm * 32 + mi * 16 + q * 4 + rr;
            #pragma unroll
            for (int ni = 0; ni < 4; ++ni) {
                const int n = n0 + wn * 64 + ni * 16 + l16;
                Ub[(size_t)m * C_ + n] = (__bf16)acc[mi][ni][rr];
            }
        }

    if (blockIdx.x == 0) {
        const int o   = m0 + (t >> 2);
        const int seg = (t & 3) * 128;
        const __bf16* wr = WoB + (size_t)o * C_ + seg;
        const float* be = Bb + b * C_ + seg;
        float s = 0.f;
        #pragma unroll
        for (int e = 0; e < 128; e += 8) {
            const bf16x8 v = *(const bf16x8*)&wr[e];
            #pragma unroll
            for (int j = 0; j < 8; ++j) s += (float)v[j] * be[e + j];
        }
        s += __shfl_xor(s, 1); s += __shfl_xor(s, 2);
        if ((t & 3) == 0) fb[b * C_ + o] = s + bo[o];
    }
}

// ---------------------------------------------------------------------------
// gemm_body (verified structure): Y[m][n] = sum_k A[m][k]*B[n][k] (+bias[m]).
// 128x128 tile, BK=64, 4 waves, gload_lds with XOR granule swizzle.
// ---------------------------------------------------------------------------
template <typename OUT_T, int OSTR, bool BIAS>
__device__ __forceinline__ void gemm_body(
    const __bf16* __restrict__ Bn, const __bf16* __restrict__ Am,
    const float* __restrict__ bias, OUT_T* __restrict__ Yb,
    int n0, int m0)
{
    __shared__ __align__(16) __bf16 As[128 * 64];
    __shared__ __align__(16) __bf16 Bs[128 * 64];

    const int t = threadIdx.x;
    const int w = t >> 6, lane = t & 63, l16 = lane & 15, q = lane >> 4;
    const int wm = w >> 1, wn = w & 1;
    const int sr = lane >> 3;
    const int sg = ((lane & 7) ^ (lane >> 3)) * 8;

    f32x4 acc[4][4] = {};

    for (int ks = 0; ks < 8; ++ks) {
        const int k0 = ks * 64;
        __syncthreads();
        #pragma unroll
        for (int p = 0; p < 4; ++p) {
            const int rb = p * 32 + w * 8;
            gload_lds16(&Am[(size_t)(m0 + rb + sr) * C_ + k0 + sg], &As[rb * 64]);
            gload_lds16(&Bn[(size_t)(n0 + rb + sr) * C_ + k0 + sg], &Bs[rb * 64]);
        }
        __syncthreads();
        #pragma unroll
        for (int kk = 0; kk < 2; ++kk) {
            const int sw = ((kk * 4 + q) ^ (l16 & 7)) * 8;
            bf16x8 af[4], bfr[4];
            #pragma unroll
            for (int mi = 0; mi < 4; ++mi)
                af[mi] = *(bf16x8*)&As[(wm * 64 + mi * 16 + l16) * 64 + sw];
            #pragma unroll
            for (int ni = 0; ni < 4; ++ni)
                bfr[ni] = *(bf16x8*)&Bs[(wn * 64 + ni * 16 + l16) * 64 + sw];
            #pragma unroll
            for (int mi = 0; mi < 4; ++mi)
                #pragma unroll
                for (int ni = 0; ni < 4; ++ni)
                    acc[mi][ni] = MFMA16(af[mi], bfr[ni], acc[mi][ni]);
        }
    }

    #pragma unroll
    for (int mi = 0; mi < 4; ++mi) {
        #pragma unroll
        for (int r = 0; r < 4; ++r) {
            const int m = m0 + wm * 64 + mi * 16 + q * 4 + r;
            const float bv_ = BIAS ? bias[m] : 0.f;
            #pragma unroll
            for (int ni = 0; ni < 4; ++ni) {
                const int n = n0 + wn * 64 + ni * 16 + l16;
                Yb[(size_t)m * OSTR + n] = (OUT_T)(acc[mi][ni][r] + bv_);
            }
        }
    }
}

// final: out[b][o][hw] = sum_c U[b][o][c] * XvT[b][hw][c] + f_b[b][o]
__global__ __launch_bounds__(256) void finalk(
    const __bf16* __restrict__ XvT, const __bf16* __restrict__ U,
    const float* __restrict__ fb, float* __restrict__ out)
{
    const int b = blockIdx.z;
    gemm_body<float, HW_, true>(XvT + (size_t)b * HW_ * C_, U + (size_t)b * C_ * C_,
                                fb + b * C_, out + (size_t)b * C_ * HW_,
                                blockIdx.x * 128, blockIdx.y * 128);
}

// ---------------------------------------------------------------------------
extern "C" void kernel_launch(void* const* d_in, const int* in_sizes, int n_in,
                              void* d_out, int out_size, void* d_ws, size_t ws_size,
                              hipStream_t stream)
{
    (void)in_sizes; (void)n_in; (void)out_size; (void)ws_size;
    const float* qf = (const float*)d_in[0];
    const float* kf = (const float*)d_in[1];
    const float* vf = (const float*)d_in[2];
    const float* Wq = (const float*)d_in[3];
    const float* bq = (const float*)d_in[4];
    const float* Wk = (const float*)d_in[5];
    const float* bk = (const float*)d_in[6];
    const float* Wv = (const float*)d_in[7];
    const float* bv = (const float*)d_in[8];
    const float* Wo = (const float*)d_in[9];
    const float* bo = (const float*)d_in[10];

    // Workspace (~66 MB of the 152 MB budget, no aliasing needed)
    __bf16* XvT  = (__bf16*)d_ws;                          // 16*2304*512
    __bf16* Gp   = XvT  + (size_t)B_ * HW_ * C_;           // 16*512*512
    __bf16* W2T  = Gp   + (size_t)B_ * C_ * C_;
    __bf16* U    = W2T  + (size_t)B_ * C_ * C_;
    __bf16* WqB  = U    + (size_t)B_ * C_ * C_;
    __bf16* WkB  = WqB  + C_ * C_;
    __bf16* WvTb = WkB  + C_ * C_;
    __bf16* WoB  = WvTb + C_ * C_;
    __bf16* Pb   = WoB  + C_ * C_;                         // 16*8*64*64
    float*  xqs  = (float*)(Pb + (size_t)B_ * NH_ * 64 * 64);
    float*  xks  = xqs + B_ * C_;
    float*  Bb   = xks + B_ * C_;
    float*  fb   = Bb  + B_ * C_;

    wprep  <<<dim3(128, 4),   256, 0, stream>>>(Wq, Wk, Wv, Wo, WqB, WkB, WvTb, WoB);
    prep   <<<dim3(18, 8, 16),256, 0, stream>>>(vf, XvT);
    gxx    <<<dim3(256),      512, 0, stream>>>(kf, qf, Gp, xks, xqs);
    scoresk<<<dim3(128),      512, 0, stream>>>(Gp, WqB, WkB, xqs, xks, bq, bk, Pb);
    pwv    <<<dim3(8, 16),    512, 0, stream>>>(Pb, WvTb, bv, W2T, Bb);
    ugemm  <<<dim3(4, 4, 16), 512, 0, stream>>>(W2T, WoB, U, Bb, bo, fb);
    finalk <<<dim3(18, 4, 16),256, 0, stream>>>(XvT, U, fb, (float*)d_out);
}